// Round 3
// baseline (52.916 us; speedup 1.0000x reference)
//
#include <hip/hip_runtime.h>
#include <hip/hip_bf16.h>

#define E_TOT 50000
#define NF    64
#define B_TOT 64
#define B_TILE 8
#define BLOCK 256
#define NCHUNK (NF / 4)   // 16 f-chunks of 4

// out[b,e] = sum_f exp(-(HL[b,f] - NL[e,f] - c[f])^2 / var[f]) * W[b,f]
// Folding: q[f] = sqrt(log2e/var[f]); A[b,f] = (HL[b,f]-c[f])*q[f];
//          nlq = NL[e,f]*q[f]; phi = exp2(-(A-nlq)^2).
// R3 change: A/W are wave-uniform -> precompute to global ws; main kernel
// reads them at uniform addresses so the compiler emits s_load (SGPR operands,
// scalar pipe) instead of ds_read_b128. No LDS, no barriers in main kernel.
//
// ws layout (floats): AW[b][i][8] = {A[b][4i..4i+3], W[b][4i..4i+3]}
//   at offset (b*NCHUNK+i)*8 ; q[64] at offset B_TOT*NCHUNK*8 = 8192.
#define WS_Q_OFF (B_TOT * NCHUNK * 8)

__global__ void prep_kernel(const float* __restrict__ NL,
                            const float* __restrict__ c,
                            const float* __restrict__ varr,
                            const float* __restrict__ NFW,
                            const int*   __restrict__ head_ids,
                            const int*   __restrict__ rel_ids,
                            float*       __restrict__ ws)
{
    const int idx = blockIdx.x * 256 + threadIdx.x;   // 0 .. 4095
    if (idx < NF) {
        ws[WS_Q_OFF + idx] = sqrtf(1.4426950408889634f / varr[idx]);
    }
    if (idx < B_TOT * NF) {
        const int b = idx >> 6;
        const int f = idx & (NF - 1);
        const float q = sqrtf(1.4426950408889634f / varr[f]);
        const int h = head_ids[b];
        const int r = rel_ids[b];
        const float a = (NL[(size_t)h * NF + f] - c[f]) * q;
        const float w = NFW[(size_t)r * NF + f];
        const int i = f >> 2, j = f & 3;
        ws[((b * NCHUNK + i) << 3) + j]     = a;
        ws[((b * NCHUNK + i) << 3) + 4 + j] = w;
    }
}

__global__ __launch_bounds__(BLOCK, 8)
void kbln_kernel(const float* __restrict__ NL,   // [E, F]
                 const float* __restrict__ AW,   // ws: [B][NCHUNK][8]
                 float*       __restrict__ out)  // [B, E]
{
    const int tid = threadIdx.x;
    const int b0  = blockIdx.y * B_TILE;
    const int e   = blockIdx.x * BLOCK + tid;
    if (e >= E_TOT) return;   // no barriers in this kernel

    const float4* nl4 = reinterpret_cast<const float4*>(NL + (size_t)e * NF);
    const float4* q4  = reinterpret_cast<const float4*>(AW + WS_Q_OFF);

    float acc[B_TILE];
#pragma unroll
    for (int bi = 0; bi < B_TILE; ++bi) acc[bi] = 0.0f;

#pragma unroll
    for (int i = 0; i < NCHUNK; ++i) {
        const float4 v = nl4[i];   // per-lane global (L1/L2-resident rows)
        const float4 q = q4[i];    // uniform -> s_load, SGPR operand
        float4 n;
        n.x = v.x * q.x; n.y = v.y * q.y; n.z = v.z * q.z; n.w = v.w * q.w;
#pragma unroll
        for (int bi = 0; bi < B_TILE; ++bi) {
            // Uniform address -> s_load_dwordx8 into SGPRs.
            const float* aw = AW + (((size_t)(b0 + bi) * NCHUNK + i) << 3);
            float t;
            t = aw[0] - n.x; acc[bi] = fmaf(__builtin_amdgcn_exp2f(-(t * t)), aw[4], acc[bi]);
            t = aw[1] - n.y; acc[bi] = fmaf(__builtin_amdgcn_exp2f(-(t * t)), aw[5], acc[bi]);
            t = aw[2] - n.z; acc[bi] = fmaf(__builtin_amdgcn_exp2f(-(t * t)), aw[6], acc[bi]);
            t = aw[3] - n.w; acc[bi] = fmaf(__builtin_amdgcn_exp2f(-(t * t)), aw[7], acc[bi]);
        }
    }

#pragma unroll
    for (int bi = 0; bi < B_TILE; ++bi) {
        out[(size_t)(b0 + bi) * E_TOT + e] = acc[bi];
    }
}

extern "C" void kernel_launch(void* const* d_in, const int* in_sizes, int n_in,
                              void* d_out, int out_size, void* d_ws, size_t ws_size,
                              hipStream_t stream)
{
    const float* NL       = (const float*)d_in[0];
    const float* c        = (const float*)d_in[1];
    const float* varr     = (const float*)d_in[2];
    const float* NFW      = (const float*)d_in[3];
    const int*   head_ids = (const int*)d_in[4];
    const int*   rel_ids  = (const int*)d_in[5];
    float*       ws       = (float*)d_ws;
    float*       out      = (float*)d_out;

    prep_kernel<<<dim3(16), dim3(256), 0, stream>>>(NL, c, varr, NFW,
                                                    head_ids, rel_ids, ws);

    dim3 grid((E_TOT + BLOCK - 1) / BLOCK, B_TOT / B_TILE);
    kbln_kernel<<<grid, dim3(BLOCK), 0, stream>>>(NL, ws, out);
}